// Round 5
// baseline (83.735 us; speedup 1.0000x reference)
//
#include <hip/hip_runtime.h>
#include <hip/hip_bf16.h>
#include <math.h>
#include <stdint.h>

// Problem constants
#define NCH   8
#define DNX   128
#define DNY   128
#define KPTS  16384

typedef __attribute__((ext_vector_type(8))) short bf16x8;   // MFMA A/B frag (8 bf16)
typedef __attribute__((ext_vector_type(4))) float f32x4;    // MFMA C/D frag

typedef const __attribute__((address_space(1))) unsigned int* gp_t;
typedef __attribute__((address_space(3))) unsigned int* lp_t;

// pack two fp32 -> one uint32 of two bf16 (RNE) via v_cvt_pk_bf16_f32
__device__ __forceinline__ uint32_t pkbf(float lo, float hi) {
    union { __hip_bfloat162 h; uint32_t u; } v;
    v.h = __float22bfloat162_rn(make_float2(lo, hi));
    return v.u;
}

// Sum over each 16-lane row via DPP (pure VALU — keeps LDS pipe free).
__device__ __forceinline__ float dpp_sum16(float v) {
    v += __int_as_float(__builtin_amdgcn_update_dpp(0, __float_as_int(v), 0xB1,  0xF, 0xF, true));
    v += __int_as_float(__builtin_amdgcn_update_dpp(0, __float_as_int(v), 0x4E,  0xF, 0xF, true));
    v += __int_as_float(__builtin_amdgcn_update_dpp(0, __float_as_int(v), 0x141, 0xF, 0xF, true));
    v += __int_as_float(__builtin_amdgcn_update_dpp(0, __float_as_int(v), 0x140, 0xF, 0xF, true));
    return v;
}

// ---------------------------------------------------------------------------
// Prep: img (fp32 planar re/im) -> B_pre (bf16, per-channel 64KB image in the
// exact LDS layout). Logical B[x][col], col = 2y+s (s=0:re, 1:im). Address:
// (256*col + 64*t4 + 16*q) ^ (16*(col&7)), x = 32*t4 + 8*q + j, +2*j.
// ---------------------------------------------------------------------------
__global__ __launch_bounds__(256) void prep_kernel(
    const float* __restrict__ img_real,
    const float* __restrict__ img_imag,
    unsigned short* __restrict__ B_pre)
{
    int tid = blockIdx.x * 256 + threadIdx.x;   // 32768 threads total
    int y  = tid & 127;
    int xc = (tid >> 7) & 15;                   // which 8-x chunk
    int s  = (tid >> 11) & 1;
    int c  = tid >> 12;
    int t4 = xc >> 2, q = xc & 3;
    int x0 = 32 * t4 + 8 * q;
    const float* src = (s ? img_imag : img_real) + c * (DNX * DNY) + y;
    float f[8];
    #pragma unroll
    for (int j = 0; j < 8; ++j) f[j] = src[(x0 + j) * DNY];
    int col  = 2 * y + s;
    int dest = (256 * col + 64 * t4 + 16 * q) ^ (16 * (col & 7));
    uint4 val;
    val.x = pkbf(f[0], f[1]);
    val.y = pkbf(f[2], f[3]);
    val.z = pkbf(f[4], f[5]);
    val.w = pkbf(f[6], f[7]);
    *(uint4*)((char*)B_pre + (size_t)c * 65536 + dest) = val;
}

// ---------------------------------------------------------------------------
// Main, round-5: SPILL-FREE + CONVOY-BREAK.
// Evidence trail: rounds 0/2/4 all give main ~37-39us regardless of barrier
// structure or nominal occupancy. Round-3 proved launch_bounds 2nd arg is
// BLOCKS/CU here ((512,4) -> 64-VGPR cap). Therefore round-4's (512,2)
// capped at 128 VGPR while live state is ~160 (pxr/pxi alone = 64) -> it was
// silently spilling ~30 regs, like every directly-observed variant so far.
//
//  * (512,1): cap 512 -> allocator takes what it needs (~160-200), ZERO
//    spill. LDS (64KB) + VGPR -> 1 block/CU resident, 2 waves/SIMD.
//  * convoy-break: all 8 waves exit the single __syncthreads in lockstep and
//    run identical [16-MFMA cluster | stage-2 VALU] phases -> pipes alternate
//    saturated/idle. Stagger wave start by ~64*w cycles via composed s_sleep
//    (wave-uniform SCC branches, zero VGPR cost) so MFMA and VALU phases of
//    different waves overlap.
//  * everything else as round 4: one channel per block, stage 64KB once via
//    global_load_lds, barrier-free ct loop, pre-XOR'd pe/po bases with
//    compile-time imm offsets, ZER C-operand init, setprio around MFMAs,
//    DPP epilogue.
// ---------------------------------------------------------------------------
__global__ __launch_bounds__(512, 1) void nudft_mfma_kernel(
    const float* __restrict__ trj,
    const unsigned short* __restrict__ B_pre,
    float* __restrict__ out)
{
    __shared__ __align__(16) unsigned short Bl[32768];   // 64 KB: whole channel

    const int t    = threadIdx.x;     // 0..511
    const int w    = t >> 6;          // wave 0..7
    const int lane = t & 63;
    const int m    = lane & 15;       // MFMA row (A) / col (C) index
    const int quad = (lane >> 4) & 3;
    const int spar = m & 1;           // col parity: 0 = re-col, 1 = im-col
    const int kb   = blockIdx.x;      // 0..63
    const int c    = blockIdx.y;      // 0..7 (channel)
    const int k0w  = kb * 256 + w * 32;

    // ---- trj loads first (compiler tracks their vmcnt independently)
    float trjx[2], tyv[8];
    #pragma unroll
    for (int kg = 0; kg < 2; ++kg)
        trjx[kg] = trj[2 * (k0w + kg * 16 + m) + 0];
    #pragma unroll
    for (int kg = 0; kg < 2; ++kg)
        #pragma unroll
        for (int r = 0; r < 4; ++r)
            tyv[kg * 4 + r] = trj[2 * (k0w + kg * 16 + quad * 4 + r) + 1];

    // ---- stage the whole 64KB channel image: 8 x 16B per thread.
    // dest = wave-uniform base + lane*16 (linear), as global_load_lds needs.
    {
        const char* g = (const char*)B_pre + ((size_t)c << 16) + (t << 4);
        char* l = (char*)&Bl[0] + (t << 4);
        #pragma unroll
        for (int i = 0; i < 8; ++i)
            __builtin_amdgcn_global_load_lds(
                (gp_t)(const void*)(g + (i << 13)),
                (lp_t)(void*)(l + (i << 13)), 16, 0, 0);
    }
    __builtin_amdgcn_sched_barrier(0);   // keep DMA issue ahead of trig setup

    // ---- A fragments (px) via incremental rotation + packed bf16 cvt:
    // A[m][x = 32*t4 + 8*quad + j]; theta(x) = d1*(x-64) pi-units, d1 = -trjx/64
    bf16x8 pxr[2][4], pxi[2][4];
    #pragma unroll
    for (int kg = 0; kg < 2; ++kg) {
        const float d1 = -trjx[kg] * (1.0f / 64.0f);
        float s1, c1;  sincospif(d1, &s1, &c1);            // rot per +1 x
        float s32, c32; sincospif(d1 * 32.0f, &s32, &c32); // rot per +32 x (t4 step)
        float ps, pc;  sincospif(d1 * (float)(8 * quad - 64), &ps, &pc);
        #pragma unroll
        for (int t4 = 0; t4 < 4; ++t4) {
            float qc = pc, qs = ps;
            float fc[8], fs[8];
            #pragma unroll
            for (int j = 0; j < 8; ++j) {
                fc[j] = qc; fs[j] = qs;
                if (j < 7) {
                    float tq = qc * c1 - qs * s1;
                    qs = fmaf(qc, s1, qs * c1);
                    qc = tq;
                }
            }
            uint32_t* pr = (uint32_t*)&pxr[kg][t4];
            uint32_t* pi = (uint32_t*)&pxi[kg][t4];
            #pragma unroll
            for (int p = 0; p < 4; ++p) {
                pr[p] = pkbf(fc[2 * p], fc[2 * p + 1]);
                pi[p] = pkbf(fs[2 * p], fs[2 * p + 1]);
            }
            if (t4 < 3) {
                float tp = pc * c32 - ps * s32;
                ps = fmaf(pc, s32, ps * c32);
                pc = tp;
            }
        }
    }

    // ---- stage-2 rotor init (directly into live cb/sb).
    // Lane element idx=(kg,r): k = k0w+kg*16+quad*4+r, y = ct*8 + ybase,
    // ybase = m>>1. (cb,sb) = cos/sin(pi * -ty*(y-64)/64); per-ct step rotor
    // (dr,di) = cos/sin(pi * -ty/8). Parity-independent.
    const int ybase = m >> 1;
    float F[8], G[8], cb[8], sb[8], dr[8], di[8];
    #pragma unroll
    for (int idx = 0; idx < 8; ++idx) {
        float ty = tyv[idx];
        float sbv, cbv; sincospif(-ty * (float)(ybase - 64) * (1.0f / 64.0f), &sbv, &cbv);
        cb[idx] = cbv; sb[idx] = sbv;
        float sd, cd; sincospif(-ty * 0.125f, &sd, &cd);
        dr[idx] = cd; di[idx] = sd;
        F[idx] = 0.f; G[idx] = 0.f;
    }

    // two pre-XOR'd LDS bases: addr(ct,t4) = (t4&1 ? po : pe)
    //                                        + 4096*ct + 128*(t4>>1)
    const int A0 = 256 * m + 16 * quad;
    const int Mx = 16 * (m & 7);
    const char* pe = (const char*)&Bl[0] + (A0 ^ Mx);
    const char* po = (const char*)&Bl[0] + ((A0 + 64) ^ Mx);
    const f32x4 ZER = {0.f, 0.f, 0.f, 0.f};

    __syncthreads();   // DMA drained; the ONLY barrier in the kernel

    // ---- convoy-break: stagger wave entry by ~64*w cycles (wave-uniform
    // branches; composed because s_sleep needs an immediate operand).
    if (w & 1) __builtin_amdgcn_s_sleep(1);
    if (w & 2) __builtin_amdgcn_s_sleep(2);
    if (w & 4) __builtin_amdgcn_s_sleep(4);

    #pragma unroll 2
    for (int ct = 0; ct < 16; ++ct) {
        bf16x8 b0 = *(const bf16x8*)(pe + 4096 * ct);
        bf16x8 b1 = *(const bf16x8*)(po + 4096 * ct);
        bf16x8 b2 = *(const bf16x8*)(pe + 4096 * ct + 128);
        bf16x8 b3 = *(const bf16x8*)(po + 4096 * ct + 128);
        f32x4 a1k0, a2k0, a1k1, a2k1;
        __builtin_amdgcn_s_setprio(1);
        a1k0 = __builtin_amdgcn_mfma_f32_16x16x32_bf16(pxr[0][0], b0, ZER,  0,0,0);
        a2k0 = __builtin_amdgcn_mfma_f32_16x16x32_bf16(pxi[0][0], b0, ZER,  0,0,0);
        a1k1 = __builtin_amdgcn_mfma_f32_16x16x32_bf16(pxr[1][0], b0, ZER,  0,0,0);
        a2k1 = __builtin_amdgcn_mfma_f32_16x16x32_bf16(pxi[1][0], b0, ZER,  0,0,0);
        a1k0 = __builtin_amdgcn_mfma_f32_16x16x32_bf16(pxr[0][1], b1, a1k0, 0,0,0);
        a2k0 = __builtin_amdgcn_mfma_f32_16x16x32_bf16(pxi[0][1], b1, a2k0, 0,0,0);
        a1k1 = __builtin_amdgcn_mfma_f32_16x16x32_bf16(pxr[1][1], b1, a1k1, 0,0,0);
        a2k1 = __builtin_amdgcn_mfma_f32_16x16x32_bf16(pxi[1][1], b1, a2k1, 0,0,0);
        a1k0 = __builtin_amdgcn_mfma_f32_16x16x32_bf16(pxr[0][2], b2, a1k0, 0,0,0);
        a2k0 = __builtin_amdgcn_mfma_f32_16x16x32_bf16(pxi[0][2], b2, a2k0, 0,0,0);
        a1k1 = __builtin_amdgcn_mfma_f32_16x16x32_bf16(pxr[1][2], b2, a1k1, 0,0,0);
        a2k1 = __builtin_amdgcn_mfma_f32_16x16x32_bf16(pxi[1][2], b2, a2k1, 0,0,0);
        a1k0 = __builtin_amdgcn_mfma_f32_16x16x32_bf16(pxr[0][3], b3, a1k0, 0,0,0);
        a2k0 = __builtin_amdgcn_mfma_f32_16x16x32_bf16(pxi[0][3], b3, a2k0, 0,0,0);
        a1k1 = __builtin_amdgcn_mfma_f32_16x16x32_bf16(pxr[1][3], b3, a1k1, 0,0,0);
        a2k1 = __builtin_amdgcn_mfma_f32_16x16x32_bf16(pxi[1][3], b3, a2k1, 0,0,0);
        __builtin_amdgcn_s_setprio(0);
        #pragma unroll
        for (int r = 0; r < 4; ++r) {
            #pragma unroll
            for (int kg = 0; kg < 2; ++kg) {
                const int idx = kg * 4 + r;
                float a1 = kg ? a1k1[r] : a1k0[r];
                float a2 = kg ? a2k1[r] : a2k0[r];
                F[idx] = fmaf(a1,  cb[idx], F[idx]);
                F[idx] = fmaf(-a2, sb[idx], F[idx]);
                G[idx] = fmaf(a1,  sb[idx], G[idx]);
                G[idx] = fmaf(a2,  cb[idx], G[idx]);
                float tz = cb[idx] * dr[idx] - sb[idx] * di[idx];
                sb[idx]  = fmaf(cb[idx], di[idx], sb[idx] * dr[idx]);
                cb[idx]  = tz;
            }
        }
    }

    // epilogue: per-lane parity assignment, 16-lane DPP reduction (VALU only)
    #pragma unroll
    for (int idx = 0; idx < 8; ++idx) {
        float kre_p = spar ? -G[idx] : F[idx];
        float kim_p = spar ?  F[idx] : G[idx];
        float kre_s = dpp_sum16(kre_p);
        float kim_s = dpp_sum16(kim_p);
        if (m == 0) {
            int kg = idx >> 2, r = idx & 3;
            int k = k0w + kg * 16 + quad * 4 + r;
            out[(size_t)c * KPTS + k]                      = kre_s;
            out[(size_t)NCH * KPTS + (size_t)c * KPTS + k] = kim_s;
        }
    }
}

extern "C" void kernel_launch(void* const* d_in, const int* in_sizes, int n_in,
                              void* d_out, int out_size, void* d_ws, size_t ws_size,
                              hipStream_t stream)
{
    const float* img_real = (const float*)d_in[0];  // (8,128,128) fp32
    const float* img_imag = (const float*)d_in[1];  // (8,128,128) fp32
    const float* trj      = (const float*)d_in[2];  // (16384,2) fp32
    float* out = (float*)d_out;                      // planar: re block then im block
    unsigned short* B_pre = (unsigned short*)d_ws;   // 512 KB bf16 pre-swizzled img

    prep_kernel<<<128, 256, 0, stream>>>(img_real, img_imag, B_pre);
    nudft_mfma_kernel<<<dim3(64, 8), 512, 0, stream>>>(trj, B_pre, out);
}

// Round 6
// 79.216 us; speedup vs baseline: 1.0571x; 1.0571x over previous
//
#include <hip/hip_runtime.h>
#include <hip/hip_bf16.h>
#include <math.h>
#include <stdint.h>

// Problem constants
#define NCH   8
#define DNX   128
#define DNY   128
#define KPTS  16384

typedef __attribute__((ext_vector_type(8))) short bf16x8;   // MFMA A/B frag (8 bf16)
typedef __attribute__((ext_vector_type(4))) float f32x4;    // MFMA C/D frag

typedef const __attribute__((address_space(1))) unsigned int* gp_t;
typedef __attribute__((address_space(3))) unsigned int* lp_t;

// pack two fp32 -> one uint32 of two bf16 (RNE) via v_cvt_pk_bf16_f32
__device__ __forceinline__ uint32_t pkbf(float lo, float hi) {
    union { __hip_bfloat162 h; uint32_t u; } v;
    v.h = __float22bfloat162_rn(make_float2(lo, hi));
    return v.u;
}

// Sum over each 16-lane row via DPP (pure VALU — keeps LDS pipe free).
__device__ __forceinline__ float dpp_sum16(float v) {
    v += __int_as_float(__builtin_amdgcn_update_dpp(0, __float_as_int(v), 0xB1,  0xF, 0xF, true));
    v += __int_as_float(__builtin_amdgcn_update_dpp(0, __float_as_int(v), 0x4E,  0xF, 0xF, true));
    v += __int_as_float(__builtin_amdgcn_update_dpp(0, __float_as_int(v), 0x141, 0xF, 0xF, true));
    v += __int_as_float(__builtin_amdgcn_update_dpp(0, __float_as_int(v), 0x140, 0xF, 0xF, true));
    return v;
}

// ---------------------------------------------------------------------------
// Prep: img (fp32 planar re/im) -> B_pre (bf16, per-channel 64KB image in the
// exact LDS layout). Logical B[x][col], col = 2y+s (s=0:re, 1:im). Address:
// (256*col + 64*t4 + 16*q) ^ (16*(col&7)), x = 32*t4 + 8*q + j, +2*j.
// ---------------------------------------------------------------------------
__global__ __launch_bounds__(256) void prep_kernel(
    const float* __restrict__ img_real,
    const float* __restrict__ img_imag,
    unsigned short* __restrict__ B_pre)
{
    int tid = blockIdx.x * 256 + threadIdx.x;   // 32768 threads total
    int y  = tid & 127;
    int xc = (tid >> 7) & 15;                   // which 8-x chunk
    int s  = (tid >> 11) & 1;
    int c  = tid >> 12;
    int t4 = xc >> 2, q = xc & 3;
    int x0 = 32 * t4 + 8 * q;
    const float* src = (s ? img_imag : img_real) + c * (DNX * DNY) + y;
    float f[8];
    #pragma unroll
    for (int j = 0; j < 8; ++j) f[j] = src[(x0 + j) * DNY];
    int col  = 2 * y + s;
    int dest = (256 * col + 64 * t4 + 16 * q) ^ (16 * (col & 7));
    uint4 val;
    val.x = pkbf(f[0], f[1]);
    val.y = pkbf(f[2], f[3]);
    val.z = pkbf(f[4], f[5]);
    val.w = pkbf(f[6], f[7]);
    *(uint4*)((char*)B_pre + (size_t)c * 65536 + dest) = val;
}

// ---------------------------------------------------------------------------
// Main, round-6: SHRINK PER-WAVE STATE UNDER THE 128-VGPR CAP.
// Evidence trail: launch_bounds 2nd arg = blocks/CU here (r3: (512,4) ->
// 64-VGPR clamp). Rounds 0/2/4 ran (x,2) -> 128-VGPR cap with ~160 live regs
// -> ALL silently spilled ~30 regs; r5 (uncapped) was spill-free but only
// 2 waves/SIMD. Same ~80us either way: spill tax == occupancy tax.
// Fix: halve per-wave k-work so live state genuinely fits 128.
//
//  * each wave owns 16 k (one kg): pxr/pxi 64->32 regs, stage-2 state
//    48->24, accs 16->8. Steady-state live ~90 VGPR.
//  * block = 8 waves = 128 k, one channel. grid (128 kb, 8 ch) = 1024
//    blocks; 2 resident blocks/CU (64KB LDS each) = 16 waves/CU =
//    4 waves/SIMD, now spill-free.
//  * total MFMA / VALU / LDS-read work unchanged (2x waves, half work each).
//  * stage once via global_load_lds (issued before trig setup), single
//    __syncthreads, barrier-free ct loop, pre-XOR'd pe/po bases with imm
//    offsets, ZER C-operand init, setprio around MFMAs, DPP epilogue.
//  * s_sleep stagger removed (r5: neutral).
// ---------------------------------------------------------------------------
__global__ __launch_bounds__(512, 2) void nudft_mfma_kernel(
    const float* __restrict__ trj,
    const unsigned short* __restrict__ B_pre,
    float* __restrict__ out)
{
    __shared__ __align__(16) unsigned short Bl[32768];   // 64 KB: whole channel

    const int t    = threadIdx.x;     // 0..511
    const int w    = t >> 6;          // wave 0..7
    const int lane = t & 63;
    const int m    = lane & 15;       // MFMA row (A) / col (C) index
    const int quad = (lane >> 4) & 3;
    const int spar = m & 1;           // col parity: 0 = re-col, 1 = im-col
    const int kb   = blockIdx.x;      // 0..127
    const int c    = blockIdx.y;      // 0..7 (channel)
    const int k0w  = kb * 128 + w * 16;   // this wave's 16 k

    // ---- trj loads first
    float trjx = trj[2 * (k0w + m) + 0];
    float tyv[4];
    #pragma unroll
    for (int r = 0; r < 4; ++r)
        tyv[r] = trj[2 * (k0w + quad * 4 + r) + 1];

    // ---- stage the whole 64KB channel image: 8 x 16B per thread.
    // dest = wave-uniform base + lane*16 (linear), as global_load_lds needs.
    {
        const char* g = (const char*)B_pre + ((size_t)c << 16) + (t << 4);
        char* l = (char*)&Bl[0] + (t << 4);
        #pragma unroll
        for (int i = 0; i < 8; ++i)
            __builtin_amdgcn_global_load_lds(
                (gp_t)(const void*)(g + (i << 13)),
                (lp_t)(void*)(l + (i << 13)), 16, 0, 0);
    }
    __builtin_amdgcn_sched_barrier(0);   // keep DMA issue ahead of trig setup

    // ---- A fragments (px) via incremental rotation + packed bf16 cvt:
    // A[m][x = 32*t4 + 8*quad + j]; theta(x) = d1*(x-64) pi-units, d1 = -trjx/64
    bf16x8 pxr[4], pxi[4];
    {
        const float d1 = -trjx * (1.0f / 64.0f);
        float s1, c1;  sincospif(d1, &s1, &c1);            // rot per +1 x
        float s32, c32; sincospif(d1 * 32.0f, &s32, &c32); // rot per +32 x (t4 step)
        float ps, pc;  sincospif(d1 * (float)(8 * quad - 64), &ps, &pc);
        #pragma unroll
        for (int t4 = 0; t4 < 4; ++t4) {
            float qc = pc, qs = ps;
            float fc[8], fs[8];
            #pragma unroll
            for (int j = 0; j < 8; ++j) {
                fc[j] = qc; fs[j] = qs;
                if (j < 7) {
                    float tq = qc * c1 - qs * s1;
                    qs = fmaf(qc, s1, qs * c1);
                    qc = tq;
                }
            }
            uint32_t* pr = (uint32_t*)&pxr[t4];
            uint32_t* pi = (uint32_t*)&pxi[t4];
            #pragma unroll
            for (int p = 0; p < 4; ++p) {
                pr[p] = pkbf(fc[2 * p], fc[2 * p + 1]);
                pi[p] = pkbf(fs[2 * p], fs[2 * p + 1]);
            }
            if (t4 < 3) {
                float tp = pc * c32 - ps * s32;
                ps = fmaf(pc, s32, ps * c32);
                pc = tp;
            }
        }
    }

    // ---- stage-2 rotor init. Lane element r: k = k0w + quad*4 + r,
    // y = ct*8 + ybase, ybase = m>>1. (cb,sb) = cos/sin(pi * -ty*(y-64)/64);
    // per-ct step rotor (dr,di) = cos/sin(pi * -ty/8). Parity-independent.
    const int ybase = m >> 1;
    float F[4], G[4], cb[4], sb[4], dr[4], di[4];
    #pragma unroll
    for (int r = 0; r < 4; ++r) {
        float ty = tyv[r];
        float sbv, cbv; sincospif(-ty * (float)(ybase - 64) * (1.0f / 64.0f), &sbv, &cbv);
        cb[r] = cbv; sb[r] = sbv;
        float sd, cd; sincospif(-ty * 0.125f, &sd, &cd);
        dr[r] = cd; di[r] = sd;
        F[r] = 0.f; G[r] = 0.f;
    }

    // two pre-XOR'd LDS bases: addr(ct,t4) = (t4&1 ? po : pe)
    //                                        + 4096*ct + 128*(t4>>1)
    const int A0 = 256 * m + 16 * quad;
    const int Mx = 16 * (m & 7);
    const char* pe = (const char*)&Bl[0] + (A0 ^ Mx);
    const char* po = (const char*)&Bl[0] + ((A0 + 64) ^ Mx);
    const f32x4 ZER = {0.f, 0.f, 0.f, 0.f};

    __syncthreads();   // DMA drained; the ONLY barrier in the kernel

    #pragma unroll 2
    for (int ct = 0; ct < 16; ++ct) {
        bf16x8 b0 = *(const bf16x8*)(pe + 4096 * ct);
        bf16x8 b1 = *(const bf16x8*)(po + 4096 * ct);
        bf16x8 b2 = *(const bf16x8*)(pe + 4096 * ct + 128);
        bf16x8 b3 = *(const bf16x8*)(po + 4096 * ct + 128);
        f32x4 a1, a2;
        __builtin_amdgcn_s_setprio(1);
        a1 = __builtin_amdgcn_mfma_f32_16x16x32_bf16(pxr[0], b0, ZER, 0,0,0);
        a2 = __builtin_amdgcn_mfma_f32_16x16x32_bf16(pxi[0], b0, ZER, 0,0,0);
        a1 = __builtin_amdgcn_mfma_f32_16x16x32_bf16(pxr[1], b1, a1,  0,0,0);
        a2 = __builtin_amdgcn_mfma_f32_16x16x32_bf16(pxi[1], b1, a2,  0,0,0);
        a1 = __builtin_amdgcn_mfma_f32_16x16x32_bf16(pxr[2], b2, a1,  0,0,0);
        a2 = __builtin_amdgcn_mfma_f32_16x16x32_bf16(pxi[2], b2, a2,  0,0,0);
        a1 = __builtin_amdgcn_mfma_f32_16x16x32_bf16(pxr[3], b3, a1,  0,0,0);
        a2 = __builtin_amdgcn_mfma_f32_16x16x32_bf16(pxi[3], b3, a2,  0,0,0);
        __builtin_amdgcn_s_setprio(0);
        #pragma unroll
        for (int r = 0; r < 4; ++r) {
            float v1 = a1[r], v2 = a2[r];
            F[r] = fmaf(v1,  cb[r], F[r]);
            F[r] = fmaf(-v2, sb[r], F[r]);
            G[r] = fmaf(v1,  sb[r], G[r]);
            G[r] = fmaf(v2,  cb[r], G[r]);
            float tz = cb[r] * dr[r] - sb[r] * di[r];
            sb[r]  = fmaf(cb[r], di[r], sb[r] * dr[r]);
            cb[r]  = tz;
        }
    }

    // epilogue: per-lane parity assignment, 16-lane DPP reduction (VALU only)
    #pragma unroll
    for (int r = 0; r < 4; ++r) {
        float kre_p = spar ? -G[r] : F[r];
        float kim_p = spar ?  F[r] : G[r];
        float kre_s = dpp_sum16(kre_p);
        float kim_s = dpp_sum16(kim_p);
        if (m == 0) {
            int k = k0w + quad * 4 + r;
            out[(size_t)c * KPTS + k]                      = kre_s;
            out[(size_t)NCH * KPTS + (size_t)c * KPTS + k] = kim_s;
        }
    }
}

extern "C" void kernel_launch(void* const* d_in, const int* in_sizes, int n_in,
                              void* d_out, int out_size, void* d_ws, size_t ws_size,
                              hipStream_t stream)
{
    const float* img_real = (const float*)d_in[0];  // (8,128,128) fp32
    const float* img_imag = (const float*)d_in[1];  // (8,128,128) fp32
    const float* trj      = (const float*)d_in[2];  // (16384,2) fp32
    float* out = (float*)d_out;                      // planar: re block then im block
    unsigned short* B_pre = (unsigned short*)d_ws;   // 512 KB bf16 pre-swizzled img

    prep_kernel<<<128, 256, 0, stream>>>(img_real, img_imag, B_pre);
    nudft_mfma_kernel<<<dim3(128, 8), 512, 0, stream>>>(trj, B_pre, out);
}